// Round 1
// baseline (646.452 us; speedup 1.0000x reference)
//
#include <hip/hip_runtime.h>
#include <math.h>

#define BATCH 4
#define HLR 256
#define WLR 256
#define HHR 512
#define WHR 512

// ---------------- Kernel 1: bicubic downsample x2 + per-channel gain ----------------
__global__ void k_down(const float* __restrict__ x, const float* __restrict__ gains,
                       float* __restrict__ out) {
    int idx = blockIdx.x * blockDim.x + threadIdx.x;
    if (idx >= BATCH * 3 * HLR * WLR) return;
    int w = idx & 255;
    int h = (idx >> 8) & 255;
    int bc = idx >> 16;          // b*3 + c
    int c = bc % 3;
    const float* src = x + (size_t)bc * (HHR * WHR);

    const float cw0 = -0.09375f, cw1 = 0.59375f, cw2 = 0.59375f, cw3 = -0.09375f;
    float acc = 0.f;
#pragma unroll
    for (int kh = 0; kh < 4; ++kh) {
        int sh = 2 * h + kh - 1;
        sh = sh < 0 ? 0 : (sh > HHR - 1 ? HHR - 1 : sh);
        const float* row = src + (size_t)sh * WHR;
        float r = 0.f;
#pragma unroll
        for (int kw = 0; kw < 4; ++kw) {
            int sw = 2 * w + kw - 1;
            sw = sw < 0 ? 0 : (sw > WHR - 1 ? WHR - 1 : sw);
            float wk = (kw == 0) ? cw0 : (kw == 1) ? cw1 : (kw == 2) ? cw2 : cw3;
            r = fmaf(wk, row[sw], r);
        }
        float wk = (kh == 0) ? cw0 : (kh == 1) ? cw1 : (kh == 2) ? cw2 : cw3;
        acc = fmaf(wk, r, acc);
    }
    out[idx] = acc * gains[c];
}

// ---------------- Kernel 2: 5x5 bilateral (reflect pad) + clip + pow(1/gamma) -------
__global__ void k_bilateral(const float* __restrict__ x, const float* __restrict__ sigp,
                            const float* __restrict__ gamp, float* __restrict__ xlr) {
    int idx = blockIdx.x * blockDim.x + threadIdx.x;
    if (idx >= BATCH * 3 * HLR * WLR) return;
    int w = idx & 255;
    int h = (idx >> 8) & 255;
    int bc = idx >> 16;
    const float* src = x + (size_t)bc * (HLR * WLR);

    float sigma = sigp[0];
    float inv2s2 = 1.0f / (2.0f * sigma * sigma);
    float invg = 1.0f / gamp[0];

    // spatial gaussian exp(-(dx^2+dy^2)/2), separable constants
    const float sp0 = 0.13533528f;  // exp(-2)
    const float sp1 = 0.60653066f;  // exp(-0.5)
    float center = src[h * WLR + w];
    float wsum = 0.f, psum = 0.f;
#pragma unroll
    for (int i = 0; i < 5; ++i) {
        int sh = h + i - 2;
        sh = sh < 0 ? -sh : (sh > HLR - 1 ? 2 * (HLR - 1) - sh : sh);  // reflect
        float spi = (i == 0 || i == 4) ? sp0 : (i == 2 ? 1.0f : sp1);
        const float* row = src + (size_t)sh * WLR;
#pragma unroll
        for (int j = 0; j < 5; ++j) {
            int sw = w + j - 2;
            sw = sw < 0 ? -sw : (sw > WLR - 1 ? 2 * (WLR - 1) - sw : sw);
            float spj = (j == 0 || j == 4) ? sp0 : (j == 2 ? 1.0f : sp1);
            float p = row[sw];
            float d = p - center;
            float cwt = expf(-d * d * inv2s2) * spi * spj;
            wsum += cwt;
            psum = fmaf(cwt, p, psum);
        }
    }
    float v = psum / (wsum + 1e-8f);
    v = fminf(fmaxf(v, 1e-8f), 1.0f);
    xlr[idx] = powf(v, invg);
}

// ---------------- Kernel 3: conv1 3->64, 5x5, pad 2, relu ----------------
// grid (16,16, B*4), block (16,16). blockIdx.z = b*4 + ocg ; 16 oc per thread.
__global__ void k_conv1(const float* __restrict__ xlr, const float* __restrict__ w1,
                        const float* __restrict__ b1, float* __restrict__ y1) {
    __shared__ float tile[20][20];
    int tx = threadIdx.x, ty = threadIdx.y;
    int tid = ty * 16 + tx;
    int w0 = blockIdx.x * 16, h0 = blockIdx.y * 16;
    int b = blockIdx.z >> 2;
    int ocg = (blockIdx.z & 3) * 16;

    float acc[16];
#pragma unroll
    for (int i = 0; i < 16; ++i) acc[i] = 0.f;

    for (int ic = 0; ic < 3; ++ic) {
        const float* src = xlr + (size_t)(b * 3 + ic) * (HLR * WLR);
        // stage 20x20 tile, zero padded (conv zero-pad)
        for (int i = tid; i < 400; i += 256) {
            int r = i / 20, cc = i % 20;
            int sh = h0 + r - 2, sw = w0 + cc - 2;
            float v = 0.f;
            if (sh >= 0 && sh < HLR && sw >= 0 && sw < WLR) v = src[sh * WLR + sw];
            tile[r][cc] = v;
        }
        __syncthreads();
#pragma unroll
        for (int kh = 0; kh < 5; ++kh) {
#pragma unroll
            for (int kw = 0; kw < 5; ++kw) {
                float v = tile[ty + kh][tx + kw];
                const float* wp = w1 + (size_t)ic * 25 + kh * 5 + kw;  // + oc*75
#pragma unroll
                for (int oc = 0; oc < 16; ++oc) {
                    acc[oc] = fmaf(v, wp[(size_t)(ocg + oc) * 75], acc[oc]);
                }
            }
        }
        __syncthreads();
    }
    int h = h0 + ty, w = w0 + tx;
#pragma unroll
    for (int oc = 0; oc < 16; ++oc) {
        float v = acc[oc] + b1[ocg + oc];
        y1[(((size_t)b * 64 + (ocg + oc)) * HLR + h) * WLR + w] = fmaxf(v, 0.f);
    }
}

// ---------------- Kernel 4: conv2 64->64, 3x3, pad 1, relu ----------------
__global__ void k_conv2(const float* __restrict__ y1, const float* __restrict__ w2,
                        const float* __restrict__ b2, float* __restrict__ y2) {
    __shared__ float tile[18][18];
    int tx = threadIdx.x, ty = threadIdx.y;
    int tid = ty * 16 + tx;
    int w0 = blockIdx.x * 16, h0 = blockIdx.y * 16;
    int b = blockIdx.z >> 2;
    int ocg = (blockIdx.z & 3) * 16;

    float acc[16];
#pragma unroll
    for (int i = 0; i < 16; ++i) acc[i] = 0.f;

    for (int ic = 0; ic < 64; ++ic) {
        const float* src = y1 + (size_t)(b * 64 + ic) * (HLR * WLR);
        for (int i = tid; i < 324; i += 256) {
            int r = i / 18, cc = i % 18;
            int sh = h0 + r - 1, sw = w0 + cc - 1;
            float v = 0.f;
            if (sh >= 0 && sh < HLR && sw >= 0 && sw < WLR) v = src[sh * WLR + sw];
            tile[r][cc] = v;
        }
        __syncthreads();
        float v[9];
#pragma unroll
        for (int kh = 0; kh < 3; ++kh)
#pragma unroll
            for (int kw = 0; kw < 3; ++kw) v[kh * 3 + kw] = tile[ty + kh][tx + kw];
#pragma unroll
        for (int oc = 0; oc < 16; ++oc) {
            const float* wp = w2 + ((size_t)(ocg + oc) * 64 + ic) * 9;  // uniform -> s_load
            float a = acc[oc];
#pragma unroll
            for (int k = 0; k < 9; ++k) a = fmaf(v[k], wp[k], a);
            acc[oc] = a;
        }
        __syncthreads();
    }
    int h = h0 + ty, w = w0 + tx;
#pragma unroll
    for (int oc = 0; oc < 16; ++oc) {
        float v = acc[oc] + b2[ocg + oc];
        y2[(((size_t)b * 64 + (ocg + oc)) * HLR + h) * WLR + w] = fmaxf(v, 0.f);
    }
}

// ---------------- Kernel 5: fused bilinear upsample x2 + conv3 64->3, 3x3, pad 1 ----
// Each thread handles one LR position (h,w) -> 2x2 HR outputs for all 3 oc.
__global__ void k_upconv3(const float* __restrict__ y2, const float* __restrict__ w3,
                          const float* __restrict__ b3, float* __restrict__ xsr) {
    __shared__ float tile[18][18];
    int tx = threadIdx.x, ty = threadIdx.y;
    int tid = ty * 16 + tx;
    int w0 = blockIdx.x * 16, h0 = blockIdx.y * 16;
    int b = blockIdx.z;
    int h = h0 + ty, w = w0 + tx;

    float acc[3][2][2];
#pragma unroll
    for (int o = 0; o < 3; ++o)
#pragma unroll
        for (int dy = 0; dy < 2; ++dy)
#pragma unroll
            for (int dx = 0; dx < 2; ++dx) acc[o][dy][dx] = 0.f;

    for (int ic = 0; ic < 64; ++ic) {
        const float* src = y2 + (size_t)(b * 64 + ic) * (HLR * WLR);
        // stage 18x18 tile with EDGE CLAMP (upsample edge semantics)
        for (int i = tid; i < 324; i += 256) {
            int r = i / 18, cc = i % 18;
            int sh = h0 + r - 1, sw = w0 + cc - 1;
            sh = sh < 0 ? 0 : (sh > HLR - 1 ? HLR - 1 : sh);
            sw = sw < 0 ? 0 : (sw > WLR - 1 ? WLR - 1 : sw);
            tile[r][cc] = src[sh * WLR + sw];
        }
        __syncthreads();

        float yv[3][3];
#pragma unroll
        for (int r = 0; r < 3; ++r)
#pragma unroll
            for (int c = 0; c < 3; ++c) yv[r][c] = tile[ty + r][tx + c];

        // horizontal upsample: t[r][4] = u columns {2w-1, 2w, 2w+1, 2w+2}
        float t[3][4];
#pragma unroll
        for (int r = 0; r < 3; ++r) {
            t[r][0] = 0.75f * yv[r][0] + 0.25f * yv[r][1];
            t[r][1] = 0.75f * yv[r][1] + 0.25f * yv[r][0];
            t[r][2] = 0.75f * yv[r][1] + 0.25f * yv[r][2];
            t[r][3] = 0.75f * yv[r][2] + 0.25f * yv[r][1];
        }
        // conv3 zero-pad at HR boundary: u col 2w-1 invalid when w==0, 2w+2 invalid when w==255
        if (w == 0) {
            t[0][0] = 0.f; t[1][0] = 0.f; t[2][0] = 0.f;
        }
        if (w == WLR - 1) {
            t[0][3] = 0.f; t[1][3] = 0.f; t[2][3] = 0.f;
        }
        // vertical upsample: u rows {2h-1, 2h, 2h+1, 2h+2}
        float u[4][4];
#pragma unroll
        for (int c = 0; c < 4; ++c) {
            u[0][c] = (h == 0) ? 0.f : 0.75f * t[0][c] + 0.25f * t[1][c];
            u[1][c] = 0.75f * t[1][c] + 0.25f * t[0][c];
            u[2][c] = 0.75f * t[1][c] + 0.25f * t[2][c];
            u[3][c] = (h == HLR - 1) ? 0.f : 0.75f * t[2][c] + 0.25f * t[1][c];
        }
#pragma unroll
        for (int o = 0; o < 3; ++o) {
            const float* wp = w3 + ((size_t)o * 64 + ic) * 9;  // uniform -> s_load
#pragma unroll
            for (int dy = 0; dy < 2; ++dy)
#pragma unroll
                for (int dx = 0; dx < 2; ++dx) {
                    float a = acc[o][dy][dx];
#pragma unroll
                    for (int oh = 0; oh < 3; ++oh)
#pragma unroll
                        for (int ow = 0; ow < 3; ++ow)
                            a = fmaf(wp[oh * 3 + ow], u[dy + oh][dx + ow], a);
                    acc[o][dy][dx] = a;
                }
        }
        __syncthreads();
    }

#pragma unroll
    for (int o = 0; o < 3; ++o) {
        float bias = b3[o];
#pragma unroll
        for (int dy = 0; dy < 2; ++dy)
#pragma unroll
            for (int dx = 0; dx < 2; ++dx) {
                xsr[((size_t)(b * 3 + o) * HHR + (2 * h + dy)) * WHR + (2 * w + dx)] =
                    acc[o][dy][dx] + bias;
            }
    }
}

extern "C" void kernel_launch(void* const* d_in, const int* in_sizes, int n_in,
                              void* d_out, int out_size, void* d_ws, size_t ws_size,
                              hipStream_t stream) {
    const float* x_hr  = (const float*)d_in[0];
    const float* gains = (const float*)d_in[1];
    const float* sigp  = (const float*)d_in[2];
    const float* gamp  = (const float*)d_in[3];
    const float* w1    = (const float*)d_in[4];
    const float* b1    = (const float*)d_in[5];
    const float* w2    = (const float*)d_in[6];
    const float* b2    = (const float*)d_in[7];
    const float* w3    = (const float*)d_in[8];
    const float* b3    = (const float*)d_in[9];

    float* out = (float*)d_out;
    float* x_sr = out;                                    // 4*3*512*512
    float* x_lr = out + (size_t)BATCH * 3 * HHR * WHR;    // 4*3*256*256

    float* ws = (float*)d_ws;
    float* tmp = ws;                                        // 786432 floats
    float* y1  = ws + 786432;                               // 16777216 floats
    float* y2  = y1 + (size_t)BATCH * 64 * HLR * WLR;       // 16777216 floats

    int nLR = BATCH * 3 * HLR * WLR;

    k_down<<<dim3((nLR + 255) / 256), dim3(256), 0, stream>>>(x_hr, gains, tmp);
    k_bilateral<<<dim3((nLR + 255) / 256), dim3(256), 0, stream>>>(tmp, sigp, gamp, x_lr);
    k_conv1<<<dim3(16, 16, BATCH * 4), dim3(16, 16), 0, stream>>>(x_lr, w1, b1, y1);
    k_conv2<<<dim3(16, 16, BATCH * 4), dim3(16, 16), 0, stream>>>(y1, w2, b2, y2);
    k_upconv3<<<dim3(16, 16, BATCH), dim3(16, 16), 0, stream>>>(y2, w3, b3, x_sr);
}

// Round 2
// 191.008 us; speedup vs baseline: 3.3844x; 3.3844x over previous
//
#include <hip/hip_runtime.h>
#include <math.h>

#define BATCH 4
#define HLR 256
#define WLR 256
#define HHR 512
#define WHR 512

typedef short s8v __attribute__((ext_vector_type(8)));
typedef float f4v __attribute__((ext_vector_type(4)));

__device__ __forceinline__ ushort f2bf(float f) {
    uint u = __builtin_bit_cast(uint, f);
    uint r = (u + 0x7FFFu + ((u >> 16) & 1u)) >> 16;
    return (ushort)r;
}
__device__ __forceinline__ float bf2f(ushort u) {
    return __builtin_bit_cast(float, ((uint)u) << 16);
}

// ---------------- Kernel 1: bicubic downsample x2 + per-channel gain ----------------
__global__ void k_down(const float* __restrict__ x, const float* __restrict__ gains,
                       float* __restrict__ out) {
    int idx = blockIdx.x * blockDim.x + threadIdx.x;
    if (idx >= BATCH * 3 * HLR * WLR) return;
    int w = idx & 255;
    int h = (idx >> 8) & 255;
    int bc = idx >> 16;
    int c = bc % 3;
    const float* src = x + (size_t)bc * (HHR * WHR);

    const float cw0 = -0.09375f, cw1 = 0.59375f, cw2 = 0.59375f, cw3 = -0.09375f;
    float acc = 0.f;
#pragma unroll
    for (int kh = 0; kh < 4; ++kh) {
        int sh = 2 * h + kh - 1;
        sh = sh < 0 ? 0 : (sh > HHR - 1 ? HHR - 1 : sh);
        const float* row = src + (size_t)sh * WHR;
        float r = 0.f;
#pragma unroll
        for (int kw = 0; kw < 4; ++kw) {
            int sw = 2 * w + kw - 1;
            sw = sw < 0 ? 0 : (sw > WHR - 1 ? WHR - 1 : sw);
            float wk = (kw == 0) ? cw0 : (kw == 1) ? cw1 : (kw == 2) ? cw2 : cw3;
            r = fmaf(wk, row[sw], r);
        }
        float wk = (kh == 0) ? cw0 : (kh == 1) ? cw1 : (kh == 2) ? cw2 : cw3;
        acc = fmaf(wk, r, acc);
    }
    out[idx] = acc * gains[c];
}

// ---------------- Kernel 2: 5x5 bilateral (reflect pad) + clip + pow(1/gamma) -------
__global__ void k_bilateral(const float* __restrict__ x, const float* __restrict__ sigp,
                            const float* __restrict__ gamp, float* __restrict__ xlr) {
    int idx = blockIdx.x * blockDim.x + threadIdx.x;
    if (idx >= BATCH * 3 * HLR * WLR) return;
    int w = idx & 255;
    int h = (idx >> 8) & 255;
    int bc = idx >> 16;
    const float* src = x + (size_t)bc * (HLR * WLR);

    float sigma = sigp[0];
    float inv2s2 = 1.0f / (2.0f * sigma * sigma);
    float invg = 1.0f / gamp[0];

    const float sp0 = 0.13533528f;  // exp(-2)
    const float sp1 = 0.60653066f;  // exp(-0.5)
    float center = src[h * WLR + w];
    float wsum = 0.f, psum = 0.f;
#pragma unroll
    for (int i = 0; i < 5; ++i) {
        int sh = h + i - 2;
        sh = sh < 0 ? -sh : (sh > HLR - 1 ? 2 * (HLR - 1) - sh : sh);
        float spi = (i == 0 || i == 4) ? sp0 : (i == 2 ? 1.0f : sp1);
        const float* row = src + (size_t)sh * WLR;
#pragma unroll
        for (int j = 0; j < 5; ++j) {
            int sw = w + j - 2;
            sw = sw < 0 ? -sw : (sw > WLR - 1 ? 2 * (WLR - 1) - sw : sw);
            float spj = (j == 0 || j == 4) ? sp0 : (j == 2 ? 1.0f : sp1);
            float p = row[sw];
            float d = p - center;
            float cwt = expf(-d * d * inv2s2) * spi * spj;
            wsum += cwt;
            psum = fmaf(cwt, p, psum);
        }
    }
    float v = psum / (wsum + 1e-8f);
    v = fminf(fmaxf(v, 1e-8f), 1.0f);
    xlr[idx] = powf(v, invg);
}

// ---------------- Kernel 3: conv1 3->64, 5x5, pad 2, relu -> y1 NHWC bf16 ----------
__global__ void k_conv1(const float* __restrict__ xlr, const float* __restrict__ w1,
                        const float* __restrict__ b1, ushort* __restrict__ y1) {
    __shared__ float tile[20][20];
    int tx = threadIdx.x, ty = threadIdx.y;
    int tid = ty * 16 + tx;
    int w0 = blockIdx.x * 16, h0 = blockIdx.y * 16;
    int b = blockIdx.z >> 2;
    int ocg = (blockIdx.z & 3) * 16;

    float acc[16];
#pragma unroll
    for (int i = 0; i < 16; ++i) acc[i] = 0.f;

    for (int ic = 0; ic < 3; ++ic) {
        const float* src = xlr + (size_t)(b * 3 + ic) * (HLR * WLR);
        for (int i = tid; i < 400; i += 256) {
            int r = i / 20, cc = i % 20;
            int sh = h0 + r - 2, sw = w0 + cc - 2;
            float v = 0.f;
            if (sh >= 0 && sh < HLR && sw >= 0 && sw < WLR) v = src[sh * WLR + sw];
            tile[r][cc] = v;
        }
        __syncthreads();
#pragma unroll
        for (int kh = 0; kh < 5; ++kh) {
#pragma unroll
            for (int kw = 0; kw < 5; ++kw) {
                float v = tile[ty + kh][tx + kw];
                const float* wp = w1 + (size_t)ic * 25 + kh * 5 + kw;
#pragma unroll
                for (int oc = 0; oc < 16; ++oc) {
                    acc[oc] = fmaf(v, wp[(size_t)(ocg + oc) * 75], acc[oc]);
                }
            }
        }
        __syncthreads();
    }
    int h = h0 + ty, w = w0 + tx;
    // pack 16 oc as bf16 -> 2x 16B stores, NHWC
    int pk[8];
#pragma unroll
    for (int q = 0; q < 8; ++q) {
        float v0 = fmaxf(acc[2 * q] + b1[ocg + 2 * q], 0.f);
        float v1 = fmaxf(acc[2 * q + 1] + b1[ocg + 2 * q + 1], 0.f);
        pk[q] = (int)f2bf(v0) | ((int)f2bf(v1) << 16);
    }
    size_t o = ((size_t)((b * HLR + h) * WLR + w) * 64 + ocg);  // ushort index
    *(int4*)(y1 + o)     = make_int4(pk[0], pk[1], pk[2], pk[3]);
    *(int4*)(y1 + o + 8) = make_int4(pk[4], pk[5], pk[6], pk[7]);
}

// ---------------- Weight prep: w2 [64][64][3][3] f32 -> Bprep[18][4][64][8] bf16 ----
__global__ void k_prepw(const float* __restrict__ w2, ushort* __restrict__ Bprep) {
    int tid = blockIdx.x * 256 + threadIdx.x;
    if (tid >= 18 * 4 * 64 * 8) return;
    int j = tid & 7;
    int l = (tid >> 3) & 63;
    int g = (tid >> 9) & 3;
    int s = tid >> 11;
    int k = 32 * s + (l >> 4) * 8 + j;  // k = tap*64 + ic
    int t = k >> 6;
    int ic = k & 63;
    int oc = g * 16 + (l & 15);
    Bprep[tid] = f2bf(w2[(size_t)(oc * 64 + ic) * 9 + t]);
}

// ---------------- Kernel 4: conv2 64->64, 3x3, pad1, relu — MFMA implicit GEMM -----
// Block: 256 thr = 4 waves. Output tile: 4 rows x 16 cols x 64 oc. Wave g -> oc block.
// y1/y2 NHWC bf16. LDS A-tile staged once; all 18 K-steps (9 taps x 2 ic-halves)
// read shifted windows of the same tile. XOR-swizzle kills the D=128 bank conflict.
__global__ void __launch_bounds__(256) k_conv2_mfma(
    const ushort* __restrict__ y1, const ushort* __restrict__ Bprep,
    const float* __restrict__ b2, ushort* __restrict__ y2) {
    __shared__ ushort lds[6 * 18 * 64];  // 13824 B
    const int tid = threadIdx.x;
    const int w0 = blockIdx.x * 16;
    const int h0 = blockIdx.y * 4;
    const int b = blockIdx.z;
    const size_t base = (size_t)b * HLR * WLR * 64;

    // stage rows h0-1..h0+4, cols w0-1..w0+16, 64 ch (zero-pad OOB)
    for (int i = tid; i < 864; i += 256) {
        int c = i & 7;       // 16B chunk = 8 ch
        int pos = i >> 3;    // 0..107 = row*18+col
        int r = pos / 18;
        int cc = pos - r * 18;
        int gh = h0 + r - 1, gw = w0 + cc - 1;
        int4 v = make_int4(0, 0, 0, 0);
        if (gh >= 0 && gh < HLR && gw >= 0 && gw < WLR)
            v = *(const int4*)(y1 + base + (size_t)(gh * WLR + gw) * 64 + c * 8);
        int byte = pos * 128 + ((c * 16) ^ ((pos & 7) << 4));
        *(int4*)((char*)lds + byte) = v;
    }
    __syncthreads();

    const int lane = tid & 63;
    const int wv = tid >> 6;     // oc group 0..3
    const int l15 = lane & 15;
    const int lgrp = lane >> 4;

    f4v acc[4];
#pragma unroll
    for (int f = 0; f < 4; ++f) acc[f] = (f4v){0.f, 0.f, 0.f, 0.f};

    const ushort* bp = Bprep + ((size_t)wv * 64 + lane) * 8;
#pragma unroll
    for (int s = 0; s < 18; ++s) {
        const int t = s >> 1;
        const int dh = t / 3 - 1;
        const int dw = t % 3 - 1;
        const int icb = (s & 1) * 64 + lgrp * 16;  // byte offset in 128B ch-vector
        s8v bfrag = *(const s8v*)(bp + (size_t)s * (4 * 64 * 8));
#pragma unroll
        for (int f = 0; f < 4; ++f) {
            int sp = (f + dh + 1) * 18 + (l15 + dw + 1);
            int byte = sp * 128 + (icb ^ ((sp & 7) << 4));
            s8v afrag = *(const s8v*)((const char*)lds + byte);
            acc[f] = __builtin_amdgcn_mfma_f32_16x16x32_bf16(afrag, bfrag, acc[f], 0, 0, 0);
        }
    }

    // epilogue: D col=lane&15 -> oc, row=(lane>>4)*4+reg -> w offset
    int oc = wv * 16 + l15;
    float bias = b2[oc];
#pragma unroll
    for (int f = 0; f < 4; ++f) {
        int h = h0 + f;
#pragma unroll
        for (int r = 0; r < 4; ++r) {
            int w = w0 + lgrp * 4 + r;
            float v = fmaxf(acc[f][r] + bias, 0.f);
            y2[base + (size_t)(h * WLR + w) * 64 + oc] = f2bf(v);
        }
    }
}

// ---------------- Kernel 5: fused upsample x2 + conv3 64->3 — NHWC bf16 input ------
__global__ void __launch_bounds__(256) k_upconv3(const ushort* __restrict__ y2,
                                                 const float* __restrict__ w3,
                                                 const float* __restrict__ b3,
                                                 float* __restrict__ xsr) {
    __shared__ ushort lds[324 * 64];  // 41472 B: 18x18 positions x 64 ch
    int tx = threadIdx.x, ty = threadIdx.y;
    int tid = ty * 16 + tx;
    int w0 = blockIdx.x * 16, h0 = blockIdx.y * 16;
    int b = blockIdx.z;
    int h = h0 + ty, w = w0 + tx;
    const size_t base = (size_t)b * HLR * WLR * 64;

    // stage 18x18x64ch once (EDGE CLAMP for upsample semantics)
    for (int i = tid; i < 2592; i += 256) {
        int c = i & 7;
        int pos = i >> 3;
        int r = pos / 18, cc = pos - r * 18;
        int gh = h0 + r - 1, gw = w0 + cc - 1;
        gh = gh < 0 ? 0 : (gh > HLR - 1 ? HLR - 1 : gh);
        gw = gw < 0 ? 0 : (gw > WLR - 1 ? WLR - 1 : gw);
        int4 v = *(const int4*)(y2 + base + (size_t)(gh * WLR + gw) * 64 + c * 8);
        int byte = pos * 128 + ((c * 16) ^ ((pos & 7) << 4));
        *(int4*)((char*)lds + byte) = v;
    }
    __syncthreads();

    float acc[3][2][2];
#pragma unroll
    for (int o = 0; o < 3; ++o)
#pragma unroll
        for (int dy = 0; dy < 2; ++dy)
#pragma unroll
            for (int dx = 0; dx < 2; ++dx) acc[o][dy][dx] = 0.f;

    for (int ic0 = 0; ic0 < 64; ic0 += 8) {
        s8v nv[9];
#pragma unroll
        for (int r = 0; r < 3; ++r)
#pragma unroll
            for (int c = 0; c < 3; ++c) {
                int pos = (ty + r) * 18 + (tx + c);
                int byte = pos * 128 + ((ic0 * 2) ^ ((pos & 7) << 4));
                nv[r * 3 + c] = *(const s8v*)((const char*)lds + byte);
            }
#pragma unroll
        for (int j = 0; j < 8; ++j) {
            int ic = ic0 + j;
            float yv[3][3];
#pragma unroll
            for (int r = 0; r < 3; ++r)
#pragma unroll
                for (int c = 0; c < 3; ++c) yv[r][c] = bf2f((ushort)nv[r * 3 + c][j]);

            float t[3][4];
#pragma unroll
            for (int r = 0; r < 3; ++r) {
                t[r][0] = 0.75f * yv[r][0] + 0.25f * yv[r][1];
                t[r][1] = 0.75f * yv[r][1] + 0.25f * yv[r][0];
                t[r][2] = 0.75f * yv[r][1] + 0.25f * yv[r][2];
                t[r][3] = 0.75f * yv[r][2] + 0.25f * yv[r][1];
            }
            if (w == 0) { t[0][0] = 0.f; t[1][0] = 0.f; t[2][0] = 0.f; }
            if (w == WLR - 1) { t[0][3] = 0.f; t[1][3] = 0.f; t[2][3] = 0.f; }
            float u[4][4];
#pragma unroll
            for (int c = 0; c < 4; ++c) {
                u[0][c] = (h == 0) ? 0.f : 0.75f * t[0][c] + 0.25f * t[1][c];
                u[1][c] = 0.75f * t[1][c] + 0.25f * t[0][c];
                u[2][c] = 0.75f * t[1][c] + 0.25f * t[2][c];
                u[3][c] = (h == HLR - 1) ? 0.f : 0.75f * t[2][c] + 0.25f * t[1][c];
            }
#pragma unroll
            for (int o = 0; o < 3; ++o) {
                const float* wp = w3 + ((size_t)o * 64 + ic) * 9;  // uniform -> s_load
#pragma unroll
                for (int dy = 0; dy < 2; ++dy)
#pragma unroll
                    for (int dx = 0; dx < 2; ++dx) {
                        float a = acc[o][dy][dx];
#pragma unroll
                        for (int oh = 0; oh < 3; ++oh)
#pragma unroll
                            for (int ow = 0; ow < 3; ++ow)
                                a = fmaf(wp[oh * 3 + ow], u[dy + oh][dx + ow], a);
                        acc[o][dy][dx] = a;
                    }
            }
        }
    }

#pragma unroll
    for (int o = 0; o < 3; ++o) {
        float bias = b3[o];
#pragma unroll
        for (int dy = 0; dy < 2; ++dy)
#pragma unroll
            for (int dx = 0; dx < 2; ++dx) {
                xsr[((size_t)(b * 3 + o) * HHR + (2 * h + dy)) * WHR + (2 * w + dx)] =
                    acc[o][dy][dx] + bias;
            }
    }
}

extern "C" void kernel_launch(void* const* d_in, const int* in_sizes, int n_in,
                              void* d_out, int out_size, void* d_ws, size_t ws_size,
                              hipStream_t stream) {
    const float* x_hr = (const float*)d_in[0];
    const float* gains = (const float*)d_in[1];
    const float* sigp = (const float*)d_in[2];
    const float* gamp = (const float*)d_in[3];
    const float* w1 = (const float*)d_in[4];
    const float* b1 = (const float*)d_in[5];
    const float* w2 = (const float*)d_in[6];
    const float* b2 = (const float*)d_in[7];
    const float* w3 = (const float*)d_in[8];
    const float* b3 = (const float*)d_in[9];

    float* out = (float*)d_out;
    float* x_sr = out;                                  // 4*3*512*512
    float* x_lr = out + (size_t)BATCH * 3 * HHR * WHR;  // 4*3*256*256

    float* ws = (float*)d_ws;
    float* tmp = ws;                                   // 786432 f32
    ushort* Bprep = (ushort*)(ws + 786432);            // 36864 bf16
    ushort* y1 = (ushort*)(ws + 786432 + 18432);       // 4*256*256*64 bf16
    ushort* y2 = y1 + (size_t)BATCH * HLR * WLR * 64;  // 4*256*256*64 bf16

    int nLR = BATCH * 3 * HLR * WLR;

    k_down<<<dim3((nLR + 255) / 256), dim3(256), 0, stream>>>(x_hr, gains, tmp);
    k_bilateral<<<dim3((nLR + 255) / 256), dim3(256), 0, stream>>>(tmp, sigp, gamp, x_lr);
    k_prepw<<<dim3(144), dim3(256), 0, stream>>>(w2, Bprep);
    k_conv1<<<dim3(16, 16, BATCH * 4), dim3(16, 16), 0, stream>>>(x_lr, w1, b1, y1);
    k_conv2_mfma<<<dim3(16, 64, BATCH), dim3(256), 0, stream>>>(y1, Bprep, b2, y2);
    k_upconv3<<<dim3(16, 16, BATCH), dim3(16, 16), 0, stream>>>(y2, w3, b3, x_sr);
}

// Round 3
// 130.539 us; speedup vs baseline: 4.9522x; 1.4632x over previous
//
#include <hip/hip_runtime.h>
#include <math.h>

#define BATCH 4
#define HLR 256
#define WLR 256
#define HHR 512
#define WHR 512

typedef short s8v __attribute__((ext_vector_type(8)));
typedef float f4v __attribute__((ext_vector_type(4)));

__device__ __forceinline__ ushort f2bf(float f) {
    uint u = __builtin_bit_cast(uint, f);
    uint r = (u + 0x7FFFu + ((u >> 16) & 1u)) >> 16;
    return (ushort)r;
}
__device__ __forceinline__ float bf2f(ushort u) {
    return __builtin_bit_cast(float, ((uint)u) << 16);
}

// ---------------- Kernel 1: bicubic downsample x2 + per-channel gain ----------------
__global__ void k_down(const float* __restrict__ x, const float* __restrict__ gains,
                       float* __restrict__ out) {
    int idx = blockIdx.x * blockDim.x + threadIdx.x;
    if (idx >= BATCH * 3 * HLR * WLR) return;
    int w = idx & 255;
    int h = (idx >> 8) & 255;
    int bc = idx >> 16;
    int c = bc % 3;
    const float* src = x + (size_t)bc * (HHR * WHR);

    const float cw0 = -0.09375f, cw1 = 0.59375f, cw2 = 0.59375f, cw3 = -0.09375f;
    float acc = 0.f;
#pragma unroll
    for (int kh = 0; kh < 4; ++kh) {
        int sh = 2 * h + kh - 1;
        sh = sh < 0 ? 0 : (sh > HHR - 1 ? HHR - 1 : sh);
        const float* row = src + (size_t)sh * WHR;
        float r = 0.f;
#pragma unroll
        for (int kw = 0; kw < 4; ++kw) {
            int sw = 2 * w + kw - 1;
            sw = sw < 0 ? 0 : (sw > WHR - 1 ? WHR - 1 : sw);
            float wk = (kw == 0) ? cw0 : (kw == 1) ? cw1 : (kw == 2) ? cw2 : cw3;
            r = fmaf(wk, row[sw], r);
        }
        float wk = (kh == 0) ? cw0 : (kh == 1) ? cw1 : (kh == 2) ? cw2 : cw3;
        acc = fmaf(wk, r, acc);
    }
    out[idx] = acc * gains[c];
}

// ---------------- Kernel 2: 5x5 bilateral (reflect pad) + clip + pow(1/gamma) -------
__global__ void k_bilateral(const float* __restrict__ x, const float* __restrict__ sigp,
                            const float* __restrict__ gamp, float* __restrict__ xlr) {
    int idx = blockIdx.x * blockDim.x + threadIdx.x;
    if (idx >= BATCH * 3 * HLR * WLR) return;
    int w = idx & 255;
    int h = (idx >> 8) & 255;
    int bc = idx >> 16;
    const float* src = x + (size_t)bc * (HLR * WLR);

    float sigma = sigp[0];
    float inv2s2 = 1.0f / (2.0f * sigma * sigma);
    float invg = 1.0f / gamp[0];

    const float sp0 = 0.13533528f;  // exp(-2)
    const float sp1 = 0.60653066f;  // exp(-0.5)
    float center = src[h * WLR + w];
    float wsum = 0.f, psum = 0.f;
#pragma unroll
    for (int i = 0; i < 5; ++i) {
        int sh = h + i - 2;
        sh = sh < 0 ? -sh : (sh > HLR - 1 ? 2 * (HLR - 1) - sh : sh);
        float spi = (i == 0 || i == 4) ? sp0 : (i == 2 ? 1.0f : sp1);
        const float* row = src + (size_t)sh * WLR;
#pragma unroll
        for (int j = 0; j < 5; ++j) {
            int sw = w + j - 2;
            sw = sw < 0 ? -sw : (sw > WLR - 1 ? 2 * (WLR - 1) - sw : sw);
            float spj = (j == 0 || j == 4) ? sp0 : (j == 2 ? 1.0f : sp1);
            float p = row[sw];
            float d = p - center;
            float cwt = __expf(-d * d * inv2s2) * spi * spj;
            wsum += cwt;
            psum = fmaf(cwt, p, psum);
        }
    }
    float v = psum / (wsum + 1e-8f);
    v = fminf(fmaxf(v, 1e-8f), 1.0f);
    xlr[idx] = __powf(v, invg);
}

// ---------------- Kernel 3: conv1 3->64, 5x5, pad 2, relu -> y1 NHWC bf16 ----------
__global__ void k_conv1(const float* __restrict__ xlr, const float* __restrict__ w1,
                        const float* __restrict__ b1, ushort* __restrict__ y1) {
    __shared__ float tile[20][20];
    int tx = threadIdx.x, ty = threadIdx.y;
    int tid = ty * 16 + tx;
    int w0 = blockIdx.x * 16, h0 = blockIdx.y * 16;
    int b = blockIdx.z >> 2;
    int ocg = (blockIdx.z & 3) * 16;

    float acc[16];
#pragma unroll
    for (int i = 0; i < 16; ++i) acc[i] = 0.f;

    for (int ic = 0; ic < 3; ++ic) {
        const float* src = xlr + (size_t)(b * 3 + ic) * (HLR * WLR);
        for (int i = tid; i < 400; i += 256) {
            int r = i / 20, cc = i % 20;
            int sh = h0 + r - 2, sw = w0 + cc - 2;
            float v = 0.f;
            if (sh >= 0 && sh < HLR && sw >= 0 && sw < WLR) v = src[sh * WLR + sw];
            tile[r][cc] = v;
        }
        __syncthreads();
#pragma unroll
        for (int kh = 0; kh < 5; ++kh) {
#pragma unroll
            for (int kw = 0; kw < 5; ++kw) {
                float v = tile[ty + kh][tx + kw];
                const float* wp = w1 + (size_t)ic * 25 + kh * 5 + kw;
#pragma unroll
                for (int oc = 0; oc < 16; ++oc) {
                    acc[oc] = fmaf(v, wp[(size_t)(ocg + oc) * 75], acc[oc]);
                }
            }
        }
        __syncthreads();
    }
    int h = h0 + ty, w = w0 + tx;
    int pk[8];
#pragma unroll
    for (int q = 0; q < 8; ++q) {
        float v0 = fmaxf(acc[2 * q] + b1[ocg + 2 * q], 0.f);
        float v1 = fmaxf(acc[2 * q + 1] + b1[ocg + 2 * q + 1], 0.f);
        pk[q] = (int)f2bf(v0) | ((int)f2bf(v1) << 16);
    }
    size_t o = ((size_t)((b * HLR + h) * WLR + w) * 64 + ocg);
    *(int4*)(y1 + o)     = make_int4(pk[0], pk[1], pk[2], pk[3]);
    *(int4*)(y1 + o + 8) = make_int4(pk[4], pk[5], pk[6], pk[7]);
}

// ---------------- Weight prep: w2 [64][64][3][3] f32 -> Bprep[18][4][64][8] bf16 ----
__global__ void k_prepw(const float* __restrict__ w2, ushort* __restrict__ Bprep) {
    int tid = blockIdx.x * 256 + threadIdx.x;
    if (tid >= 18 * 4 * 64 * 8) return;
    int j = tid & 7;
    int l = (tid >> 3) & 63;
    int g = (tid >> 9) & 3;
    int s = tid >> 11;
    int k = 32 * s + (l >> 4) * 8 + j;
    int t = k >> 6;
    int ic = k & 63;
    int oc = g * 16 + (l & 15);
    Bprep[tid] = f2bf(w2[(size_t)(oc * 64 + ic) * 9 + t]);
}

// ---------------- Kernel 4: conv2 64->64, 3x3, pad1, relu — MFMA implicit GEMM -----
__global__ void __launch_bounds__(256) k_conv2_mfma(
    const ushort* __restrict__ y1, const ushort* __restrict__ Bprep,
    const float* __restrict__ b2, ushort* __restrict__ y2) {
    __shared__ ushort lds[6 * 18 * 64];  // 13824 B
    const int tid = threadIdx.x;
    const int w0 = blockIdx.x * 16;
    const int h0 = blockIdx.y * 4;
    const int b = blockIdx.z;
    const size_t base = (size_t)b * HLR * WLR * 64;

    for (int i = tid; i < 864; i += 256) {
        int c = i & 7;
        int pos = i >> 3;
        int r = pos / 18;
        int cc = pos - r * 18;
        int gh = h0 + r - 1, gw = w0 + cc - 1;
        int4 v = make_int4(0, 0, 0, 0);
        if (gh >= 0 && gh < HLR && gw >= 0 && gw < WLR)
            v = *(const int4*)(y1 + base + (size_t)(gh * WLR + gw) * 64 + c * 8);
        int byte = pos * 128 + ((c * 16) ^ ((pos & 7) << 4));
        *(int4*)((char*)lds + byte) = v;
    }
    __syncthreads();

    const int lane = tid & 63;
    const int wv = tid >> 6;
    const int l15 = lane & 15;
    const int lgrp = lane >> 4;

    f4v acc[4];
#pragma unroll
    for (int f = 0; f < 4; ++f) acc[f] = (f4v){0.f, 0.f, 0.f, 0.f};

    const ushort* bp = Bprep + ((size_t)wv * 64 + lane) * 8;
#pragma unroll
    for (int s = 0; s < 18; ++s) {
        const int t = s >> 1;
        const int dh = t / 3 - 1;
        const int dw = t % 3 - 1;
        const int icb = (s & 1) * 64 + lgrp * 16;
        s8v bfrag = *(const s8v*)(bp + (size_t)s * (4 * 64 * 8));
#pragma unroll
        for (int f = 0; f < 4; ++f) {
            int sp = (f + dh + 1) * 18 + (l15 + dw + 1);
            int byte = sp * 128 + (icb ^ ((sp & 7) << 4));
            s8v afrag = *(const s8v*)((const char*)lds + byte);
            acc[f] = __builtin_amdgcn_mfma_f32_16x16x32_bf16(afrag, bfrag, acc[f], 0, 0, 0);
        }
    }

    int oc = wv * 16 + l15;
    float bias = b2[oc];
#pragma unroll
    for (int f = 0; f < 4; ++f) {
        int h = h0 + f;
#pragma unroll
        for (int r = 0; r < 4; ++r) {
            int w = w0 + lgrp * 4 + r;
            float v = fmaxf(acc[f][r] + bias, 0.f);
            y2[base + (size_t)(h * WLR + w) * 64 + oc] = f2bf(v);
        }
    }
}

// --------- Effective upsample weight: Av(d, e_idx, t_idx), taps t-1 in {-1..2} -----
__device__ __forceinline__ float Avf(int d, int e, int t) {
    int mm = d + e - 1;                 // u-row offset relative to 2h
    int par = mm & 1;
    int jr = (mm - par) >> 1;           // 0.75 contribution tap offset
    int j2 = jr + (par ? 1 : -1);       // 0.25 contribution tap offset
    float a = 0.f;
    if (t == jr + 1) a += 0.75f;
    if (t == j2 + 1) a += 0.25f;
    return a;
}

// --------- Weight prep: Weff -> Bprep3[32][64][8] bf16 (N cols = p*3+o, 12 used) ---
__global__ void k_prepw3(const float* __restrict__ w3, ushort* __restrict__ Bp) {
    int tid = blockIdx.x * 256 + threadIdx.x;
    if (tid >= 32 * 64 * 8) return;
    int j = tid & 7;
    int l = (tid >> 3) & 63;
    int s = tid >> 9;
    int col = l & 15;
    float v = 0.f;
    if (col < 12) {
        int p = col / 3, o = col % 3;
        int dy = p >> 1, dx = p & 1;
        int k = s * 32 + (l >> 4) * 8 + j;
        int tap = k >> 6, ic = k & 63;
        int ty = tap >> 2, tx = tap & 3;
#pragma unroll
        for (int oh = 0; oh < 3; ++oh)
#pragma unroll
            for (int ow = 0; ow < 3; ++ow)
                v += w3[(size_t)(o * 64 + ic) * 9 + oh * 3 + ow] *
                     Avf(dy, oh, ty) * Avf(dx, ow, tx);
    }
    Bp[tid] = f2bf(v);
}

// ---------------- Kernel 5: fused upsample+conv3 as MFMA 4x4-tap 64->12 conv -------
// Block 256 = 4 waves; block covers 16x16 LR pixels (wave wv -> rows wv*4..+3).
// LDS: 19x19 positions x 64ch, edge-clamped, XOR-swizzled. Interior+near-edge HR
// pixels exact; the 1-pixel HR frame is fixed up by k_fix3 afterwards.
__global__ void __launch_bounds__(256) k_upc3_mfma(
    const ushort* __restrict__ y2, const ushort* __restrict__ Bp,
    const float* __restrict__ b3, float* __restrict__ xsr) {
    __shared__ ushort lds[19 * 19 * 64];  // 46208 B
    const int tid = threadIdx.x;
    const int w0 = blockIdx.x * 16;
    const int h0 = blockIdx.y * 16;
    const int b = blockIdx.z;
    const size_t base = (size_t)b * HLR * WLR * 64;

    for (int i = tid; i < 2888; i += 256) {
        int c = i & 7;
        int pos = i >> 3;
        int r = pos / 19, cc = pos - r * 19;
        int gh = h0 + r - 1, gw = w0 + cc - 1;
        gh = gh < 0 ? 0 : (gh > HLR - 1 ? HLR - 1 : gh);
        gw = gw < 0 ? 0 : (gw > WLR - 1 ? WLR - 1 : gw);
        int4 v = *(const int4*)(y2 + base + (size_t)(gh * WLR + gw) * 64 + c * 8);
        int byte = pos * 128 + ((c * 16) ^ ((pos & 7) << 4));
        *(int4*)((char*)lds + byte) = v;
    }
    __syncthreads();

    const int lane = tid & 63;
    const int wv = tid >> 6;
    const int l15 = lane & 15;
    const int lgrp = lane >> 4;
    const int rowbase = wv * 4;

    f4v acc[4];
#pragma unroll
    for (int f = 0; f < 4; ++f) acc[f] = (f4v){0.f, 0.f, 0.f, 0.f};

    const ushort* bp = Bp + (size_t)lane * 8;
#pragma unroll
    for (int s = 0; s < 32; ++s) {
        s8v bfrag = *(const s8v*)(bp + (size_t)s * 512);
        const int tap = s >> 1;
        const int ty = tap >> 2, tx = tap & 3;
        const int icb = (s & 1) * 64 + lgrp * 16;
#pragma unroll
        for (int f = 0; f < 4; ++f) {
            int pos = (rowbase + f + ty) * 19 + (l15 + tx);
            int byte = pos * 128 + (icb ^ ((pos & 7) << 4));
            s8v afrag = *(const s8v*)((const char*)lds + byte);
            acc[f] = __builtin_amdgcn_mfma_f32_16x16x32_bf16(afrag, bfrag, acc[f], 0, 0, 0);
        }
    }

    if (l15 < 12) {
        int p = l15 / 3, o = l15 - p * 3;
        int dy = p >> 1, dx = p & 1;
        float bias = b3[o];
        const size_t obase = (size_t)(b * 3 + o) * HHR * WHR;
#pragma unroll
        for (int f = 0; f < 4; ++f) {
            int n = 2 * (h0 + rowbase + f) + dy;
#pragma unroll
            for (int r = 0; r < 4; ++r) {
                int m = 2 * (w0 + lgrp * 4 + r) + dx;
                xsr[obase + (size_t)n * WHR + m] = acc[f][r] + bias;
            }
        }
    }
}

// ---------------- Boundary fixup: recompute the 1-pixel HR frame (wave/pixel) ------
__global__ void k_fix3(const ushort* __restrict__ y2, const float* __restrict__ w3,
                       const float* __restrict__ b3, float* __restrict__ xsr) {
    int wid = (blockIdx.x * blockDim.x + threadIdx.x) >> 6;
    int lane = threadIdx.x & 63;
    if (wid >= BATCH * 3 * 2044) return;
    int b = wid / (3 * 2044);
    int rem = wid - b * (3 * 2044);
    int o = rem / 2044;
    int p = rem - o * 2044;
    int n, m;
    if (p < 512) { n = 0; m = p; }
    else if (p < 1024) { n = 511; m = p - 512; }
    else if (p < 1534) { n = p - 1024 + 1; m = 0; }
    else { n = p - 1534 + 1; m = 511; }

    const int ic = lane;
    const ushort* Y = y2 + (size_t)b * HLR * WLR * 64 + ic;
    float acc = 0.f;
#pragma unroll
    for (int oh = 0; oh < 3; ++oh) {
        int r = n - 1 + oh;
        if (r < 0 || r >= HHR) continue;
        int pr = r & 1;
        int jr = (r - pr) >> 1;
        int j2 = jr + (pr ? 1 : -1);
        j2 = j2 < 0 ? 0 : (j2 > HLR - 1 ? HLR - 1 : j2);
#pragma unroll
        for (int ow = 0; ow < 3; ++ow) {
            int c = m - 1 + ow;
            if (c < 0 || c >= WHR) continue;
            int pc = c & 1;
            int kc = (c - pc) >> 1;
            int k2 = kc + (pc ? 1 : -1);
            k2 = k2 < 0 ? 0 : (k2 > WLR - 1 ? WLR - 1 : k2);
            float y00 = bf2f(Y[(size_t)(jr * WLR + kc) * 64]);
            float y01 = bf2f(Y[(size_t)(jr * WLR + k2) * 64]);
            float y10 = bf2f(Y[(size_t)(j2 * WLR + kc) * 64]);
            float y11 = bf2f(Y[(size_t)(j2 * WLR + k2) * 64]);
            float u = 0.5625f * y00 + 0.1875f * y01 + 0.1875f * y10 + 0.0625f * y11;
            acc = fmaf(w3[(size_t)(o * 64 + ic) * 9 + oh * 3 + ow], u, acc);
        }
    }
#pragma unroll
    for (int off = 32; off; off >>= 1) acc += __shfl_xor(acc, off, 64);
    if (lane == 0) xsr[((size_t)(b * 3 + o) * HHR + n) * WHR + m] = acc + b3[o];
}

extern "C" void kernel_launch(void* const* d_in, const int* in_sizes, int n_in,
                              void* d_out, int out_size, void* d_ws, size_t ws_size,
                              hipStream_t stream) {
    const float* x_hr = (const float*)d_in[0];
    const float* gains = (const float*)d_in[1];
    const float* sigp = (const float*)d_in[2];
    const float* gamp = (const float*)d_in[3];
    const float* w1 = (const float*)d_in[4];
    const float* b1 = (const float*)d_in[5];
    const float* w2 = (const float*)d_in[6];
    const float* b2 = (const float*)d_in[7];
    const float* w3 = (const float*)d_in[8];
    const float* b3 = (const float*)d_in[9];

    float* out = (float*)d_out;
    float* x_sr = out;                                  // 4*3*512*512
    float* x_lr = out + (size_t)BATCH * 3 * HHR * WHR;  // 4*3*256*256

    float* ws = (float*)d_ws;
    float* tmp = ws;                                    // 786432 f32
    ushort* Bprep = (ushort*)(ws + 786432);             // 36864 bf16
    ushort* y1 = (ushort*)(ws + 786432 + 18432);        // 4*256*256*64 bf16
    ushort* y2 = y1 + (size_t)BATCH * HLR * WLR * 64;   // 4*256*256*64 bf16
    ushort* Bprep3 = y2 + (size_t)BATCH * HLR * WLR * 64;  // 16384 bf16

    int nLR = BATCH * 3 * HLR * WLR;

    k_down<<<dim3((nLR + 255) / 256), dim3(256), 0, stream>>>(x_hr, gains, tmp);
    k_bilateral<<<dim3((nLR + 255) / 256), dim3(256), 0, stream>>>(tmp, sigp, gamp, x_lr);
    k_prepw<<<dim3(144), dim3(256), 0, stream>>>(w2, Bprep);
    k_prepw3<<<dim3(64), dim3(256), 0, stream>>>(w3, Bprep3);
    k_conv1<<<dim3(16, 16, BATCH * 4), dim3(16, 16), 0, stream>>>(x_lr, w1, b1, y1);
    k_conv2_mfma<<<dim3(16, 64, BATCH), dim3(256), 0, stream>>>(y1, Bprep, b2, y2);
    k_upc3_mfma<<<dim3(16, 16, BATCH), dim3(256), 0, stream>>>(y2, Bprep3, b3, x_sr);
    k_fix3<<<dim3((BATCH * 3 * 2044 * 64 + 255) / 256), dim3(256), 0, stream>>>(y2, w3, b3, x_sr);
}

// Round 4
// 105.534 us; speedup vs baseline: 6.1255x; 1.2369x over previous
//
#include <hip/hip_runtime.h>
#include <math.h>

#define BATCH 4
#define HLR 256
#define WLR 256
#define HHR 512
#define WHR 512

typedef short s8v __attribute__((ext_vector_type(8)));
typedef float f4v __attribute__((ext_vector_type(4)));

__device__ __forceinline__ ushort f2bf(float f) {
    uint u = __builtin_bit_cast(uint, f);
    uint r = (u + 0x7FFFu + ((u >> 16) & 1u)) >> 16;
    return (ushort)r;
}
__device__ __forceinline__ float bf2f(ushort u) {
    return __builtin_bit_cast(float, ((uint)u) << 16);
}

// ---------------- Kernel 1: bicubic downsample x2 + per-channel gain ----------------
__global__ void k_down(const float* __restrict__ x, const float* __restrict__ gains,
                       float* __restrict__ out) {
    int idx = blockIdx.x * blockDim.x + threadIdx.x;
    if (idx >= BATCH * 3 * HLR * WLR) return;
    int w = idx & 255;
    int h = (idx >> 8) & 255;
    int bc = idx >> 16;
    int c = bc % 3;
    const float* src = x + (size_t)bc * (HHR * WHR);

    const float cw0 = -0.09375f, cw1 = 0.59375f, cw2 = 0.59375f, cw3 = -0.09375f;
    float acc = 0.f;
#pragma unroll
    for (int kh = 0; kh < 4; ++kh) {
        int sh = 2 * h + kh - 1;
        sh = sh < 0 ? 0 : (sh > HHR - 1 ? HHR - 1 : sh);
        const float* row = src + (size_t)sh * WHR;
        float r = 0.f;
#pragma unroll
        for (int kw = 0; kw < 4; ++kw) {
            int sw = 2 * w + kw - 1;
            sw = sw < 0 ? 0 : (sw > WHR - 1 ? WHR - 1 : sw);
            float wk = (kw == 0) ? cw0 : (kw == 1) ? cw1 : (kw == 2) ? cw2 : cw3;
            r = fmaf(wk, row[sw], r);
        }
        float wk = (kh == 0) ? cw0 : (kh == 1) ? cw1 : (kh == 2) ? cw2 : cw3;
        acc = fmaf(wk, r, acc);
    }
    out[idx] = acc * gains[c];
}

// ---------------- Kernel 2: 5x5 bilateral (reflect pad) + clip + pow(1/gamma) -------
__global__ void k_bilateral(const float* __restrict__ x, const float* __restrict__ sigp,
                            const float* __restrict__ gamp, float* __restrict__ xlr) {
    int idx = blockIdx.x * blockDim.x + threadIdx.x;
    if (idx >= BATCH * 3 * HLR * WLR) return;
    int w = idx & 255;
    int h = (idx >> 8) & 255;
    int bc = idx >> 16;
    const float* src = x + (size_t)bc * (HLR * WLR);

    float sigma = sigp[0];
    float inv2s2 = 1.0f / (2.0f * sigma * sigma);
    float invg = 1.0f / gamp[0];

    const float sp0 = 0.13533528f;  // exp(-2)
    const float sp1 = 0.60653066f;  // exp(-0.5)
    float center = src[h * WLR + w];
    float wsum = 0.f, psum = 0.f;
#pragma unroll
    for (int i = 0; i < 5; ++i) {
        int sh = h + i - 2;
        sh = sh < 0 ? -sh : (sh > HLR - 1 ? 2 * (HLR - 1) - sh : sh);
        float spi = (i == 0 || i == 4) ? sp0 : (i == 2 ? 1.0f : sp1);
        const float* row = src + (size_t)sh * WLR;
#pragma unroll
        for (int j = 0; j < 5; ++j) {
            int sw = w + j - 2;
            sw = sw < 0 ? -sw : (sw > WLR - 1 ? 2 * (WLR - 1) - sw : sw);
            float spj = (j == 0 || j == 4) ? sp0 : (j == 2 ? 1.0f : sp1);
            float p = row[sw];
            float d = p - center;
            float cwt = __expf(-d * d * inv2s2) * spi * spj;
            wsum += cwt;
            psum = fmaf(cwt, p, psum);
        }
    }
    float v = psum / (wsum + 1e-8f);
    v = fminf(fmaxf(v, 1e-8f), 1.0f);
    xlr[idx] = __powf(v, invg);
}

// --------- Weight prep conv1: w1[64][3][5][5] -> Bprep1[3][4][64][8] bf16, K=96 ----
// k = tap*3 + ic (tap = kh*5+kw), zero-padded k in [75,96)
__global__ void k_prepw1(const float* __restrict__ w1, ushort* __restrict__ Bp) {
    int tid = blockIdx.x * 256 + threadIdx.x;
    if (tid >= 3 * 4 * 64 * 8) return;
    int j = tid & 7;
    int l = (tid >> 3) & 63;
    int g = (tid >> 9) & 3;
    int s = tid >> 11;
    int k = s * 32 + (l >> 4) * 8 + j;
    int oc = g * 16 + (l & 15);
    float v = 0.f;
    if (k < 75) {
        int tap = k / 3, ic = k % 3;
        v = w1[(size_t)oc * 75 + ic * 25 + tap];
    }
    Bp[tid] = f2bf(v);
}

// ---------------- Kernel 3: conv1 3->64, 5x5, pad 2, relu — MFMA implicit GEMM ----
// Block 256 = 4 waves = 4 oc groups; output tile 4 rows x 16 cols x 64 oc.
// im2col A built in LDS: A[64 pos][104 pitch] bf16, pos = f*16 + wl, k = tap*3+ic.
__global__ void __launch_bounds__(256) k_conv1_mfma(
    const float* __restrict__ xlr, const ushort* __restrict__ Bp,
    const float* __restrict__ b1, ushort* __restrict__ y1) {
    __shared__ float rawt[3][8][20];                 // 1920 B, zero-padded halo
    __shared__ __align__(16) ushort Alds[64 * 104];  // 13312 B
    const int tid = threadIdx.x;
    const int w0 = blockIdx.x * 16;
    const int h0 = blockIdx.y * 4;
    const int b = blockIdx.z;

    // stage raw halo tile: rows h0-2..h0+5, cols w0-2..w0+17, 3 ch, zero-pad OOB
    for (int i = tid; i < 480; i += 256) {
        int ch = i / 160;
        int rem = i - ch * 160;
        int r = rem / 20, c = rem - r * 20;
        int gh = h0 + r - 2, gw = w0 + c - 2;
        float v = 0.f;
        if (gh >= 0 && gh < HLR && gw >= 0 && gw < WLR)
            v = xlr[(size_t)(b * 3 + ch) * (HLR * WLR) + gh * WLR + gw];
        rawt[ch][r][c] = v;
    }
    __syncthreads();

    // im2col: thread -> pos = tid>>2 (f*16+wl), kq = tid&3 -> k in [kq*24, kq*24+24)
    {
        const int pos = tid >> 2;
        const int kq = tid & 3;
        const int f = pos >> 4;
        const int wl = pos & 15;
#pragma unroll
        for (int m = 0; m < 3; ++m) {
            uint pk[4];
#pragma unroll
            for (int e2 = 0; e2 < 4; ++e2) {
                ushort lo, hi;
#pragma unroll
                for (int h2 = 0; h2 < 2; ++h2) {
                    int i = m * 8 + e2 * 2 + h2;
                    int t0 = i / 3;          // compile-time
                    int ic = i - t0 * 3;     // compile-time
                    int tap = kq * 8 + t0;   // runtime
                    float val = 0.f;
                    if (tap < 25) {
                        int kh = tap / 5, kw = tap - (tap / 5) * 5;
                        val = rawt[ic][f + kh][wl + kw];
                    }
                    if (h2 == 0) lo = f2bf(val); else hi = f2bf(val);
                }
                pk[e2] = (uint)lo | ((uint)hi << 16);
            }
            *(int4*)(Alds + pos * 104 + kq * 24 + m * 8) =
                make_int4(pk[0], pk[1], pk[2], pk[3]);
        }
    }
    __syncthreads();

    const int lane = tid & 63;
    const int wv = tid >> 6;
    const int l15 = lane & 15;
    const int lgrp = lane >> 4;

    f4v acc[4];
#pragma unroll
    for (int f = 0; f < 4; ++f) acc[f] = (f4v){0.f, 0.f, 0.f, 0.f};

#pragma unroll
    for (int s = 0; s < 3; ++s) {
        s8v bfrag = *(const s8v*)(Bp + ((size_t)(s * 4 + wv) * 64 + lane) * 8);
#pragma unroll
        for (int f = 0; f < 4; ++f) {
            const ushort* ap = Alds + (f * 16 + l15) * 104 + s * 32 + lgrp * 8;
            s8v afrag = *(const s8v*)ap;
            acc[f] = __builtin_amdgcn_mfma_f32_16x16x32_bf16(afrag, bfrag, acc[f], 0, 0, 0);
        }
    }

    int oc = wv * 16 + l15;
    float bias = b1[oc];
    const size_t base = (size_t)b * HLR * WLR * 64;
#pragma unroll
    for (int f = 0; f < 4; ++f) {
        int h = h0 + f;
#pragma unroll
        for (int r = 0; r < 4; ++r) {
            int w = w0 + lgrp * 4 + r;
            float v = fmaxf(acc[f][r] + bias, 0.f);
            y1[base + (size_t)(h * WLR + w) * 64 + oc] = f2bf(v);
        }
    }
}

// ---------------- Weight prep: w2 [64][64][3][3] f32 -> Bprep[18][4][64][8] bf16 ----
__global__ void k_prepw(const float* __restrict__ w2, ushort* __restrict__ Bprep) {
    int tid = blockIdx.x * 256 + threadIdx.x;
    if (tid >= 18 * 4 * 64 * 8) return;
    int j = tid & 7;
    int l = (tid >> 3) & 63;
    int g = (tid >> 9) & 3;
    int s = tid >> 11;
    int k = 32 * s + (l >> 4) * 8 + j;
    int t = k >> 6;
    int ic = k & 63;
    int oc = g * 16 + (l & 15);
    Bprep[tid] = f2bf(w2[(size_t)(oc * 64 + ic) * 9 + t]);
}

// ---------------- Kernel 4: conv2 64->64, 3x3, pad1, relu — MFMA implicit GEMM -----
__global__ void __launch_bounds__(256) k_conv2_mfma(
    const ushort* __restrict__ y1, const ushort* __restrict__ Bprep,
    const float* __restrict__ b2, ushort* __restrict__ y2) {
    __shared__ ushort lds[6 * 18 * 64];  // 13824 B
    const int tid = threadIdx.x;
    const int w0 = blockIdx.x * 16;
    const int h0 = blockIdx.y * 4;
    const int b = blockIdx.z;
    const size_t base = (size_t)b * HLR * WLR * 64;

    for (int i = tid; i < 864; i += 256) {
        int c = i & 7;
        int pos = i >> 3;
        int r = pos / 18;
        int cc = pos - r * 18;
        int gh = h0 + r - 1, gw = w0 + cc - 1;
        int4 v = make_int4(0, 0, 0, 0);
        if (gh >= 0 && gh < HLR && gw >= 0 && gw < WLR)
            v = *(const int4*)(y1 + base + (size_t)(gh * WLR + gw) * 64 + c * 8);
        int byte = pos * 128 + ((c * 16) ^ ((pos & 7) << 4));
        *(int4*)((char*)lds + byte) = v;
    }
    __syncthreads();

    const int lane = tid & 63;
    const int wv = tid >> 6;
    const int l15 = lane & 15;
    const int lgrp = lane >> 4;

    f4v acc[4];
#pragma unroll
    for (int f = 0; f < 4; ++f) acc[f] = (f4v){0.f, 0.f, 0.f, 0.f};

    const ushort* bp = Bprep + ((size_t)wv * 64 + lane) * 8;
#pragma unroll
    for (int s = 0; s < 18; ++s) {
        const int t = s >> 1;
        const int dh = t / 3 - 1;
        const int dw = t % 3 - 1;
        const int icb = (s & 1) * 64 + lgrp * 16;
        s8v bfrag = *(const s8v*)(bp + (size_t)s * (4 * 64 * 8));
#pragma unroll
        for (int f = 0; f < 4; ++f) {
            int sp = (f + dh + 1) * 18 + (l15 + dw + 1);
            int byte = sp * 128 + (icb ^ ((sp & 7) << 4));
            s8v afrag = *(const s8v*)((const char*)lds + byte);
            acc[f] = __builtin_amdgcn_mfma_f32_16x16x32_bf16(afrag, bfrag, acc[f], 0, 0, 0);
        }
    }

    int oc = wv * 16 + l15;
    float bias = b2[oc];
#pragma unroll
    for (int f = 0; f < 4; ++f) {
        int h = h0 + f;
#pragma unroll
        for (int r = 0; r < 4; ++r) {
            int w = w0 + lgrp * 4 + r;
            float v = fmaxf(acc[f][r] + bias, 0.f);
            y2[base + (size_t)(h * WLR + w) * 64 + oc] = f2bf(v);
        }
    }
}

// --------- Effective upsample weight: Av(d, e_idx, t_idx), taps t-1 in {-1..2} -----
__device__ __forceinline__ float Avf(int d, int e, int t) {
    int mm = d + e - 1;
    int par = mm & 1;
    int jr = (mm - par) >> 1;
    int j2 = jr + (par ? 1 : -1);
    float a = 0.f;
    if (t == jr + 1) a += 0.75f;
    if (t == j2 + 1) a += 0.25f;
    return a;
}

// --------- Weight prep: Weff -> Bprep3[32][64][8] bf16 (N cols = p*3+o, 12 used) ---
__global__ void k_prepw3(const float* __restrict__ w3, ushort* __restrict__ Bp) {
    int tid = blockIdx.x * 256 + threadIdx.x;
    if (tid >= 32 * 64 * 8) return;
    int j = tid & 7;
    int l = (tid >> 3) & 63;
    int s = tid >> 9;
    int col = l & 15;
    float v = 0.f;
    if (col < 12) {
        int p = col / 3, o = col % 3;
        int dy = p >> 1, dx = p & 1;
        int k = s * 32 + (l >> 4) * 8 + j;
        int tap = k >> 6, ic = k & 63;
        int ty = tap >> 2, tx = tap & 3;
#pragma unroll
        for (int oh = 0; oh < 3; ++oh)
#pragma unroll
            for (int ow = 0; ow < 3; ++ow)
                v += w3[(size_t)(o * 64 + ic) * 9 + oh * 3 + ow] *
                     Avf(dy, oh, ty) * Avf(dx, ow, tx);
    }
    Bp[tid] = f2bf(v);
}

// ---------------- Kernel 5: fused upsample+conv3 as MFMA 4x4-tap 64->12 conv -------
__global__ void __launch_bounds__(256) k_upc3_mfma(
    const ushort* __restrict__ y2, const ushort* __restrict__ Bp,
    const float* __restrict__ b3, float* __restrict__ xsr) {
    __shared__ ushort lds[19 * 19 * 64];  // 46208 B
    const int tid = threadIdx.x;
    const int w0 = blockIdx.x * 16;
    const int h0 = blockIdx.y * 16;
    const int b = blockIdx.z;
    const size_t base = (size_t)b * HLR * WLR * 64;

    for (int i = tid; i < 2888; i += 256) {
        int c = i & 7;
        int pos = i >> 3;
        int r = pos / 19, cc = pos - r * 19;
        int gh = h0 + r - 1, gw = w0 + cc - 1;
        gh = gh < 0 ? 0 : (gh > HLR - 1 ? HLR - 1 : gh);
        gw = gw < 0 ? 0 : (gw > WLR - 1 ? WLR - 1 : gw);
        int4 v = *(const int4*)(y2 + base + (size_t)(gh * WLR + gw) * 64 + c * 8);
        int byte = pos * 128 + ((c * 16) ^ ((pos & 7) << 4));
        *(int4*)((char*)lds + byte) = v;
    }
    __syncthreads();

    const int lane = tid & 63;
    const int wv = tid >> 6;
    const int l15 = lane & 15;
    const int lgrp = lane >> 4;
    const int rowbase = wv * 4;

    f4v acc[4];
#pragma unroll
    for (int f = 0; f < 4; ++f) acc[f] = (f4v){0.f, 0.f, 0.f, 0.f};

    const ushort* bp = Bp + (size_t)lane * 8;
#pragma unroll
    for (int s = 0; s < 32; ++s) {
        s8v bfrag = *(const s8v*)(bp + (size_t)s * 512);
        const int tap = s >> 1;
        const int ty = tap >> 2, tx = tap & 3;
        const int icb = (s & 1) * 64 + lgrp * 16;
#pragma unroll
        for (int f = 0; f < 4; ++f) {
            int pos = (rowbase + f + ty) * 19 + (l15 + tx);
            int byte = pos * 128 + (icb ^ ((pos & 7) << 4));
            s8v afrag = *(const s8v*)((const char*)lds + byte);
            acc[f] = __builtin_amdgcn_mfma_f32_16x16x32_bf16(afrag, bfrag, acc[f], 0, 0, 0);
        }
    }

    if (l15 < 12) {
        int p = l15 / 3, o = l15 - p * 3;
        int dy = p >> 1, dx = p & 1;
        float bias = b3[o];
        const size_t obase = (size_t)(b * 3 + o) * HHR * WHR;
#pragma unroll
        for (int f = 0; f < 4; ++f) {
            int n = 2 * (h0 + rowbase + f) + dy;
#pragma unroll
            for (int r = 0; r < 4; ++r) {
                int m = 2 * (w0 + lgrp * 4 + r) + dx;
                xsr[obase + (size_t)n * WHR + m] = acc[f][r] + bias;
            }
        }
    }
}

// ---------------- Boundary fixup: recompute the 1-pixel HR frame (wave/pixel) ------
__global__ void k_fix3(const ushort* __restrict__ y2, const float* __restrict__ w3,
                       const float* __restrict__ b3, float* __restrict__ xsr) {
    int wid = (blockIdx.x * blockDim.x + threadIdx.x) >> 6;
    int lane = threadIdx.x & 63;
    if (wid >= BATCH * 3 * 2044) return;
    int b = wid / (3 * 2044);
    int rem = wid - b * (3 * 2044);
    int o = rem / 2044;
    int p = rem - o * 2044;
    int n, m;
    if (p < 512) { n = 0; m = p; }
    else if (p < 1024) { n = 511; m = p - 512; }
    else if (p < 1534) { n = p - 1024 + 1; m = 0; }
    else { n = p - 1534 + 1; m = 511; }

    const int ic = lane;
    const ushort* Y = y2 + (size_t)b * HLR * WLR * 64 + ic;
    float acc = 0.f;
#pragma unroll
    for (int oh = 0; oh < 3; ++oh) {
        int r = n - 1 + oh;
        if (r < 0 || r >= HHR) continue;
        int pr = r & 1;
        int jr = (r - pr) >> 1;
        int j2 = jr + (pr ? 1 : -1);
        j2 = j2 < 0 ? 0 : (j2 > HLR - 1 ? HLR - 1 : j2);
#pragma unroll
        for (int ow = 0; ow < 3; ++ow) {
            int c = m - 1 + ow;
            if (c < 0 || c >= WHR) continue;
            int pc = c & 1;
            int kc = (c - pc) >> 1;
            int k2 = kc + (pc ? 1 : -1);
            k2 = k2 < 0 ? 0 : (k2 > WLR - 1 ? WLR - 1 : k2);
            float y00 = bf2f(Y[(size_t)(jr * WLR + kc) * 64]);
            float y01 = bf2f(Y[(size_t)(jr * WLR + k2) * 64]);
            float y10 = bf2f(Y[(size_t)(j2 * WLR + kc) * 64]);
            float y11 = bf2f(Y[(size_t)(j2 * WLR + k2) * 64]);
            float u = 0.5625f * y00 + 0.1875f * y01 + 0.1875f * y10 + 0.0625f * y11;
            acc = fmaf(w3[(size_t)(o * 64 + ic) * 9 + oh * 3 + ow], u, acc);
        }
    }
#pragma unroll
    for (int off = 32; off; off >>= 1) acc += __shfl_xor(acc, off, 64);
    if (lane == 0) xsr[((size_t)(b * 3 + o) * HHR + n) * WHR + m] = acc + b3[o];
}

extern "C" void kernel_launch(void* const* d_in, const int* in_sizes, int n_in,
                              void* d_out, int out_size, void* d_ws, size_t ws_size,
                              hipStream_t stream) {
    const float* x_hr = (const float*)d_in[0];
    const float* gains = (const float*)d_in[1];
    const float* sigp = (const float*)d_in[2];
    const float* gamp = (const float*)d_in[3];
    const float* w1 = (const float*)d_in[4];
    const float* b1 = (const float*)d_in[5];
    const float* w2 = (const float*)d_in[6];
    const float* b2 = (const float*)d_in[7];
    const float* w3 = (const float*)d_in[8];
    const float* b3 = (const float*)d_in[9];

    float* out = (float*)d_out;
    float* x_sr = out;                                  // 4*3*512*512
    float* x_lr = out + (size_t)BATCH * 3 * HHR * WHR;  // 4*3*256*256

    float* ws = (float*)d_ws;
    float* tmp = ws;                                    // 786432 f32
    ushort* Bprep = (ushort*)(ws + 786432);             // 36864 bf16
    ushort* y1 = (ushort*)(ws + 786432 + 18432);        // 4*256*256*64 bf16
    ushort* y2 = y1 + (size_t)BATCH * HLR * WLR * 64;   // 4*256*256*64 bf16
    ushort* Bprep3 = y2 + (size_t)BATCH * HLR * WLR * 64;  // 16384 bf16
    ushort* Bprep1 = Bprep3 + 16384;                    // 6144 bf16

    int nLR = BATCH * 3 * HLR * WLR;

    k_down<<<dim3((nLR + 255) / 256), dim3(256), 0, stream>>>(x_hr, gains, tmp);
    k_bilateral<<<dim3((nLR + 255) / 256), dim3(256), 0, stream>>>(tmp, sigp, gamp, x_lr);
    k_prepw<<<dim3(144), dim3(256), 0, stream>>>(w2, Bprep);
    k_prepw3<<<dim3(64), dim3(256), 0, stream>>>(w3, Bprep3);
    k_prepw1<<<dim3(24), dim3(256), 0, stream>>>(w1, Bprep1);
    k_conv1_mfma<<<dim3(16, 64, BATCH), dim3(256), 0, stream>>>(x_lr, Bprep1, b1, y1);
    k_conv2_mfma<<<dim3(16, 64, BATCH), dim3(256), 0, stream>>>(y1, Bprep, b2, y2);
    k_upc3_mfma<<<dim3(16, 16, BATCH), dim3(256), 0, stream>>>(y2, Bprep3, b3, x_sr);
    k_fix3<<<dim3((BATCH * 3 * 2044 * 64 + 255) / 256), dim3(256), 0, stream>>>(y2, w3, b3, x_sr);
}